// Round 8
// baseline (6539.688 us; speedup 1.0000x reference)
//
#include <hip/hip_runtime.h>

#define DEV __device__ __forceinline__

typedef __attribute__((ext_vector_type(4))) int i32x4;

// ---------------------------------------------------------------------------
// TernaryMVAdapter forward on MI355X. Round 7: replay-divergence bisect.
// Base = round-5 (passed post-timing). Kept from round 6:
//  * k_dgemm bank-conflict-free LDS ([m][k]+pad, interleaved maps) — proven
//    bitwise-identical accumulation order, barrier-separated LDS phases.
//  * k_rsq8 LDS-free (reads const input twice; trivially deterministic).
// REVERTED: k_qgemm back to the proven 256-thread / 4-wave version (the
// 512-thread variant is the prime suspect for the replay divergence).
// ---------------------------------------------------------------------------

struct WList { const float* p[37]; long long n[37]; };
struct WOffs { long long o[37]; };

// ---------------- fused deterministic |w| sums (37 slots) ------------------
__global__ void k_abssum_all(WList wl, double* __restrict__ partials)
{
    const int slot = blockIdx.y;
    const float* w = wl.p[slot];
    const long long n = wl.n[slot];
    __shared__ double sm[256];
    double s = 0.0;
    for (long long i = (long long)blockIdx.x*256 + threadIdx.x; i < n; i += 32LL*256)
        s += (double)fabsf(w[i]);
    sm[threadIdx.x] = s;
    __syncthreads();
    for (int k = 128; k > 0; k >>= 1) {
        if ((int)threadIdx.x < k) sm[threadIdx.x] += sm[threadIdx.x + k];
        __syncthreads();
    }
    if (threadIdx.x == 0) partials[slot*32 + blockIdx.x] = sm[0];
}

__global__ void k_abssum_fin(const double* __restrict__ partials, double* __restrict__ out)
{
    const int slot = blockIdx.x;
    if (threadIdx.x == 0) {
        double s = 0.0;
        for (int i = 0; i < 32; ++i) s += partials[slot*32 + i];
        out[slot] = s;
    }
}

// ---------------- one-time weight ternarization (f64-exact decision) -------
__global__ void k_ternarize(WList wl, WOffs wo, const double* __restrict__ scales,
                            signed char* __restrict__ W8)
{
    const int slot = blockIdx.y;
    const float* w = wl.p[slot];
    const long long n4 = wl.n[slot] >> 2;           // all sizes divisible by 4
    const double dqw = fmax(scales[slot] / (double)wl.n[slot], 1e-5);
    const double thr = 0.5 * dqw;
    signed char* o = W8 + wo.o[slot];
    for (long long i = (long long)blockIdx.x*256 + threadIdx.x; i < n4; i += 64LL*256) {
        float4 v = *reinterpret_cast<const float4*>(w + i*4);
        float we[4] = {v.x, v.y, v.z, v.w};
        char r[4];
#pragma unroll
        for (int e = 0; e < 4; ++e) {
            double wd = (double)we[e];
            r[e] = (char)((wd > thr) - (wd < -thr));
        }
        *reinterpret_cast<char4*>(o + i*4) = make_char4(r[0], r[1], r[2], r[3]);
    }
}

// ---------------- timestep frequency embedding (f64) -----------------------
__global__ void k_temb(const float* __restrict__ t, double* __restrict__ out)
{
    int b = blockIdx.x, j = threadIdx.x;               // 8 x 128
    double fr  = exp(-9.210340371976184 * (double)j / 128.0);
    double ang = (double)t[b] * fr;
    out[b*256 + j]       = cos(ang);
    out[b*256 + 128 + j] = sin(ang);
}

// ---------------- rmsnorm + int8 absmax quant (f64, LDS-free) --------------
template<typename TI>
__global__ void k_rsq8(const TI* __restrict__ x, signed char* __restrict__ q8,
                       double* __restrict__ dscale, int K, int pre_silu)
{
    __shared__ double red[256], red2[256];
    const int row = blockIdx.x, tid = threadIdx.x;
    const TI* xr = x + (size_t)row*K;
    double ss = 0.0, am = 0.0;
    for (int i = tid; i < K; i += 256) {
        double v = (double)xr[i];
        if (pre_silu) v = v / (1.0 + exp(-v));
        ss += v*v; am = fmax(am, fabs(v));
    }
    red[tid] = ss; red2[tid] = am;
    __syncthreads();
    for (int s = 128; s > 0; s >>= 1) {
        if (tid < s) { red[tid] += red[tid+s]; red2[tid] = fmax(red2[tid], red2[tid+s]); }
        __syncthreads();
    }
    double rms = 1.0 / sqrt(red[0]/(double)K + 1e-8);
    double s   = 127.0 / fmax(red2[0]*rms, 1e-5);
    signed char* orow = q8 + (size_t)row*K;
    for (int i = tid; i < K; i += 256) {
        double v = (double)xr[i];
        if (pre_silu) v = v / (1.0 + exp(-v));
        orow[i] = (signed char)(int)fmin(fmax(rint(v*rms*s), -128.0), 127.0);
    }
    if (tid == 0) dscale[row] = s;
}

// ---------------- layernorm(+gb/+mod) + rmsnorm + int8 quant (f64) ---------
__global__ void k_lnq8(const double* __restrict__ x, signed char* __restrict__ q8,
                       double* __restrict__ dscale, int K,
                       const float* __restrict__ gamma, const float* __restrict__ beta,
                       const double* __restrict__ sh, const double* __restrict__ sc,
                       int modstride, double eps)
{
    extern __shared__ double rb[];
    __shared__ double red[256], red2[256];
    const int row = blockIdx.x, tid = threadIdx.x;
    const double* xr = x + (size_t)row*K;
    double s1 = 0.0;
    for (int i = tid; i < K; i += 256) { double v = xr[i]; rb[i] = v; s1 += v; }
    red[tid] = s1; __syncthreads();
    for (int s = 128; s > 0; s >>= 1) { if (tid < s) red[tid] += red[tid+s]; __syncthreads(); }
    double mu = red[0]/(double)K;
    __syncthreads();
    double s2 = 0.0;
    for (int i = tid; i < K; i += 256) { double d = rb[i]-mu; s2 += d*d; }
    red[tid] = s2; __syncthreads();
    for (int s = 128; s > 0; s >>= 1) { if (tid < s) red[tid] += red[tid+s]; __syncthreads(); }
    double r = 1.0 / sqrt(red[0]/(double)K + eps);
    const int bn = row >> 8;
    __syncthreads();
    double ss = 0.0, am = 0.0;
    for (int i = tid; i < K; i += 256) {
        double y = (rb[i]-mu)*r;
        if (gamma) y = y*(double)gamma[i] + (double)beta[i];
        if (sh)    y = y*(1.0 + sc[(size_t)bn*modstride + i]) + sh[(size_t)bn*modstride + i];
        rb[i] = y; ss += y*y; am = fmax(am, fabs(y));
    }
    red[tid] = ss; red2[tid] = am;
    __syncthreads();
    for (int s = 128; s > 0; s >>= 1) {
        if (tid < s) { red[tid] += red[tid+s]; red2[tid] = fmax(red2[tid], red2[tid+s]); }
        __syncthreads();
    }
    double rms = 1.0 / sqrt(red[0]/(double)K + 1e-8);
    double s   = 127.0 / fmax(red2[0]*rms, 1e-5);
    signed char* orow = q8 + (size_t)row*K;
    for (int i = tid; i < K; i += 256)
        orow[i] = (signed char)(int)fmin(fmax(rint(rb[i]*rms*s), -128.0), 127.0);
    if (tid == 0) dscale[row] = s;
}

// ---------------- ogate (rmsnorm*g*sig(g)) + rmsnorm + quant (f64) ---------
__global__ void k_ogateq8(const double* __restrict__ O, const double* __restrict__ G,
                          signed char* __restrict__ q8, double* __restrict__ dscale, int K)
{
    extern __shared__ double rb[];
    __shared__ double red[256], red2[256];
    const int row = blockIdx.x, tid = threadIdx.x;
    const double* orow = O + (size_t)row*K;
    const double* grow = G + (size_t)row*K;
    double ss = 0.0;
    for (int i = tid; i < K; i += 256) { double v = orow[i]; rb[i] = v; ss += v*v; }
    red[tid] = ss; __syncthreads();
    for (int s = 128; s > 0; s >>= 1) { if (tid < s) red[tid] += red[tid+s]; __syncthreads(); }
    double rmso = 1.0 / sqrt(red[0]/(double)K + 1e-8);
    __syncthreads();
    double ss2 = 0.0, am = 0.0;
    for (int i = tid; i < K; i += 256) {
        double g = grow[i];
        double y = rb[i]*rmso * g / (1.0 + exp(-g));
        rb[i] = y; ss2 += y*y; am = fmax(am, fabs(y));
    }
    red[tid] = ss2; red2[tid] = am;
    __syncthreads();
    for (int s = 128; s > 0; s >>= 1) {
        if (tid < s) { red[tid] += red[tid+s]; red2[tid] = fmax(red2[tid], red2[tid+s]); }
        __syncthreads();
    }
    double rms = 1.0 / sqrt(red[0]/(double)K + 1e-8);
    double s   = 127.0 / fmax(red2[0]*rms, 1e-5);
    signed char* qrow = q8 + (size_t)row*K;
    for (int i = tid; i < K; i += 256)
        qrow[i] = (signed char)(int)fmin(fmax(rint(rb[i]*rms*s), -128.0), 127.0);
    if (tid == 0) dscale[row] = s;
}

// ---------------- HGRN gate precompute + lean serial scan ------------------
__global__ void k_gatepre(double* __restrict__ F, double* __restrict__ I, long long n)
{
    long long i = (long long)blockIdx.x*256 + threadIdx.x;
    if (i >= n) return;
    double fp = F[i], ip = I[i];
    double f = 1.0/(1.0+exp(-fp));
    double v = (ip/(1.0+exp(-ip)))*(1.0-f);
    F[i] = f; I[i] = v;
}

__global__ void k_scan2(const double* __restrict__ F, const double* __restrict__ V,
                        double* __restrict__ O, int n_outer, long long outer_stride,
                        int n_inner, long long t_stride, int T)
{
    long long chain = (long long)blockIdx.x*blockDim.x + threadIdx.x;
    if (chain >= (long long)n_outer*n_inner) return;
    long long base = (chain / n_inner)*outer_stride + (chain % n_inner);
    double h = 0.0;
    for (int t = 0; t < T; ++t) {
        long long idx = base + (long long)t*t_stride;
        h = F[idx]*h + V[idx];
        O[idx] = h;
    }
}

// ---------------- misc elementwise (f64) -----------------------------------
__global__ void k_add(const double* __restrict__ a, const double* __restrict__ b,
                      double* __restrict__ o, int n)
{
    int i = blockIdx.x*256 + threadIdx.x;
    if (i < n) o[i] = a[i] + b[i];
}

__global__ void k_resid_attn(double* __restrict__ xt, const double* __restrict__ acc,
                             const double* __restrict__ refo, const double* __restrict__ mod)
{
    int idx = blockIdx.x*256 + threadIdx.x;            // 2048*1152 exact
    int r = idx / 1152, d = idx - r*1152;
    int bn = r >> 8, l = r & 255;
    double ga = mod[(size_t)bn*6912 + 2*1152 + d];
    double rv = refo[((size_t)((bn>>2)*256 + l))*1152 + d];
    xt[idx] += ga*(acc[idx] + rv);
}

__global__ void k_resid_mlp(double* __restrict__ xt, const double* __restrict__ t2,
                            const double* __restrict__ mod)
{
    int idx = blockIdx.x*256 + threadIdx.x;
    int r = idx / 1152, d = idx - r*1152;
    int bn = r >> 8;
    xt[idx] += mod[(size_t)bn*6912 + 5*1152 + d] * t2[idx];
}

// xt = patchify(x)@xe_w + xe_b + pos + feats0   (f64)
__global__ void k_patchify(const float* __restrict__ x, const float* __restrict__ w,
                           const float* __restrict__ bias, const float* __restrict__ pos,
                           const double* __restrict__ f0, double* __restrict__ xt)
{
    int idx = blockIdx.x*256 + threadIdx.x;            // 2048*1152 exact
    int r = idx / 1152, o = idx - r*1152;
    int bn = r >> 8, p = r & 255;
    int y = p >> 4, xx = p & 15;
    double acc = (double)bias[o] + (double)pos[(size_t)p*1152 + o] + f0[idx];
#pragma unroll
    for (int c = 0; c < 4; ++c)
#pragma unroll
        for (int ky = 0; ky < 2; ++ky)
#pragma unroll
            for (int kx = 0; kx < 2; ++kx)
                acc += (double)x[((size_t)(bn*4 + c)*32 + 2*y+ky)*32 + 2*xx+kx]
                     * (double)w[o*16 + c*4 + ky*2 + kx];
    xt[idx] = acc;
}

__global__ void k_unpatch(const double* __restrict__ flo, float* __restrict__ out)
{
    int idx = blockIdx.x*256 + threadIdx.x;            // 65536 exact
    int xx = idx & 31, y = (idx>>5)&31, ch = (idx>>10)&7, b = idx>>13;
    int hp = y>>1, py = y&1, wp = xx>>1, px = xx&1;
    out[idx] = (float)flo[((size_t)(b*256 + hp*16 + wp))*32 + (py*2+px)*8 + ch];
}

// ---------------- f64 SIMT GEMM, bank-conflict-free LDS --------------------
// As[m][k]/Ws[n][k] with +1 pad; thread covers cols {tx,tx+16,tx+32,tx+48},
// rows {ty,ty+16,ty+32,ty+48}. Compute reads: A broadcast (4 addrs, distinct
// banks), W 16 addrs over 16 distinct bank-pairs. Per-output k-accumulation
// order unchanged -> bitwise-identical C (verified: first-call absmax equal).
template<int AMODE>
DEV void load_a4d(const void* __restrict__ A, int row, int k, int M, double o[4])
{
    if (row >= M) { o[0]=o[1]=o[2]=o[3]=0.0; return; }
    if constexpr (AMODE == 1) {
        const float* Af = (const float*)A;
        int b = row>>10, p = row&1023, oy = p>>5, ox = p&31;
        int c = k>>8, ky = (k>>4)&15, kx = k&15;
        float4 v = *reinterpret_cast<const float4*>(
            Af + (((size_t)(b*6+c)*512 + (size_t)(oy*16+ky))*512 + (size_t)(ox*16+kx)));
        o[0]=v.x; o[1]=v.y; o[2]=v.z; o[3]=v.w;
    } else {
        const double* Ad = (const double*)A;
        int b = row>>8, y = (row>>4)&15, x = row&15;
        int q = k/1152, c = k - q*1152, ky = q>>1, kx = q&1;
        const double* p = Ad + (size_t)(b*1024 + (2*y+ky)*32 + 2*x+kx)*1152 + c;
        o[0]=p[0]; o[1]=p[1]; o[2]=p[2]; o[3]=p[3];
    }
}

template<int WMODE>
DEV void load_w4d(const float* __restrict__ W, int row, int k, int Nb, int K, double o[4])
{
    if (row >= Nb) { o[0]=o[1]=o[2]=o[3]=0.0; return; }
    if constexpr (WMODE == 0) {
        float4 v = *reinterpret_cast<const float4*>(W + (size_t)row*K + k);
        o[0]=v.x; o[1]=v.y; o[2]=v.z; o[3]=v.w;
    } else {
        int q = k/1152, c = k - q*1152;
        const float* p = W + (size_t)row*4608 + (size_t)c*4 + q;
        o[0]=p[0]; o[1]=p[4]; o[2]=p[8]; o[3]=p[12];
    }
}

template<int AMODE, int WMODE>
__global__ __launch_bounds__(256)
void k_dgemm(const void* __restrict__ A, const float* __restrict__ W,
             const float* __restrict__ bias, double* __restrict__ C,
             int M, int N, int K)
{
    __shared__ double As[64][17];                  // [m][k], pad kills conflicts
    __shared__ double Ws[64][17];                  // [n][k]
    const int tid = threadIdx.x;
    const int tx = tid & 15, ty = tid >> 4;
    const int m0 = blockIdx.y*64, n0 = blockIdx.x*64;
    const int lr = tid >> 2;                       // staging row 0..63
    const int lc = (tid & 3) * 4;                  // staging k {0,4,8,12}

    double acc[4][4] = {};

    for (int kt = 0; kt < K; kt += 16) {
        {
            double v[4];
            load_a4d<AMODE>(A, m0+lr, kt+lc, M, v);
            As[lr][lc+0]=v[0]; As[lr][lc+1]=v[1]; As[lr][lc+2]=v[2]; As[lr][lc+3]=v[3];
        }
        {
            double wv[4];
            load_w4d<WMODE>(W, n0+lr, kt+lc, N, K, wv);
            Ws[lr][lc+0]=wv[0]; Ws[lr][lc+1]=wv[1]; Ws[lr][lc+2]=wv[2]; Ws[lr][lc+3]=wv[3];
        }
        __syncthreads();
#pragma unroll
        for (int k = 0; k < 16; ++k) {
            double a[4], b[4];
#pragma unroll
            for (int e = 0; e < 4; ++e) { a[e] = As[ty + 16*e][k]; b[e] = Ws[tx + 16*e][k]; }
#pragma unroll
            for (int i = 0; i < 4; ++i)
#pragma unroll
                for (int j = 0; j < 4; ++j) acc[i][j] += a[i]*b[j];
        }
        __syncthreads();
    }

#pragma unroll
    for (int i = 0; i < 4; ++i) {
        int row = m0 + ty + 16*i;
        if (row >= M) continue;
#pragma unroll
        for (int j = 0; j < 4; ++j) {
            int col = n0 + tx + 16*j;
            if (col >= N) continue;
            C[(size_t)row*N + col] = acc[i][j] + (bias ? (double)bias[col] : 0.0);
        }
    }
}

// ---------------- int8 MFMA GEMM (exact), 256 thr / 4 waves (PROVEN r5) ----
// PRE=1: W8 = pre-ternarized int8 [N(,2N)][K]; PRE=0: ternarize Wf on the fly.
template<int GATE, int PRE>
__global__ __launch_bounds__(256)
void k_qgemm(const signed char* __restrict__ A8, const double* __restrict__ ascale,
             const float* __restrict__ Wf, const signed char* __restrict__ W8,
             const double* __restrict__ wsum, long long wcount,
             const float* __restrict__ bias, double* __restrict__ C,
             int M, int N, int K, int accum)
{
    __shared__ __align__(16) signed char Als[4][128][16];
    __shared__ __align__(16) signed char Bls[4][128][16];
    __shared__ __align__(16) signed char B2ls[GATE?4:1][GATE?128:1][16];
    const int tid = threadIdx.x;
    const int lane = tid & 63, wid = tid >> 6;
    const int wr = wid >> 1, wc = wid & 1;             // 2x2 waves, 64x64 each
    const int m0 = blockIdx.x*128, n0 = blockIdx.y*128;
    const int ks = lane >> 4, fr = lane & 15;

    const double dqw = fmax(*wsum / (double)wcount, 1e-5);  // mean|w|
    const double thr = 0.5 * dqw;                           // ternary threshold

    i32x4 acc[4][4];
    i32x4 acc2[GATE?4:1][4];
#pragma unroll
    for (int i = 0; i < 4; ++i)
#pragma unroll
        for (int j = 0; j < 4; ++j) {
            acc[i][j] = i32x4{0,0,0,0};
            if constexpr (GATE) acc2[i][j] = i32x4{0,0,0,0};
        }

    for (int kt = 0; kt < K; kt += 64) {
#pragma unroll
        for (int c = 0; c < 2; ++c) {
            int idx = tid + c*256;
            int row = idx & 127, kslot = idx >> 7;
            i32x4 v = {0,0,0,0};
            if (m0 + row < M)
                v = *reinterpret_cast<const i32x4*>(A8 + (size_t)(m0+row)*K + kt + kslot*16);
            *reinterpret_cast<i32x4*>(&Als[kslot][row][0]) = v;
        }
#pragma unroll
        for (int c = 0; c < 2; ++c) {
            int idx = tid + c*256;
            int row = idx & 127, kslot = idx >> 7;
            i32x4 pv = {0,0,0,0};
            if (n0 + row < N) {
                if constexpr (PRE) {
                    pv = *reinterpret_cast<const i32x4*>(W8 + (size_t)(n0+row)*K + kt + kslot*16);
                } else {
                    const float* wp = Wf + (size_t)(n0+row)*K + kt + kslot*16;
#pragma unroll
                    for (int d = 0; d < 4; ++d) {
                        float4 wv = *reinterpret_cast<const float4*>(wp + d*4);
                        float we[4] = {wv.x, wv.y, wv.z, wv.w};
                        unsigned p = 0;
#pragma unroll
                        for (int e = 0; e < 4; ++e) {
                            double wd = (double)we[e];
                            int q = (wd > thr) - (wd < -thr);
                            p |= ((unsigned)(q & 255)) << (8*e);
                        }
                        pv[d] = (int)p;
                    }
                }
            }
            *reinterpret_cast<i32x4*>(&Bls[kslot][row][0]) = pv;
        }
        if constexpr (GATE) {
#pragma unroll
            for (int c = 0; c < 2; ++c) {
                int idx = tid + c*256;
                int row = idx & 127, kslot = idx >> 7;
                i32x4 pv = {0,0,0,0};
                if (n0 + row < N) {
                    if constexpr (PRE) {
                        pv = *reinterpret_cast<const i32x4*>(W8 + (size_t)(n0+row+N)*K + kt + kslot*16);
                    } else {
                        const float* wp = Wf + (size_t)(n0+row+N)*K + kt + kslot*16;
#pragma unroll
                        for (int d = 0; d < 4; ++d) {
                            float4 wv = *reinterpret_cast<const float4*>(wp + d*4);
                            float we[4] = {wv.x, wv.y, wv.z, wv.w};
                            unsigned p = 0;
#pragma unroll
                            for (int e = 0; e < 4; ++e) {
                                double wd = (double)we[e];
                                int q = (wd > thr) - (wd < -thr);
                                p |= ((unsigned)(q & 255)) << (8*e);
                            }
                            pv[d] = (int)p;
                        }
                    }
                }
                *reinterpret_cast<i32x4*>(&B2ls[kslot][row][0]) = pv;
            }
        }
        __syncthreads();
        i32x4 a[4];
#pragma unroll
        for (int i = 0; i < 4; ++i)
            a[i] = *reinterpret_cast<const i32x4*>(&Als[ks][wr*64 + i*16 + fr][0]);
#pragma unroll
        for (int j = 0; j < 4; ++j) {
            i32x4 b = *reinterpret_cast<const i32x4*>(&Bls[ks][wc*64 + j*16 + fr][0]);
#pragma unroll
            for (int i = 0; i < 4; ++i)
                acc[i][j] = __builtin_amdgcn_mfma_i32_16x16x64_i8(a[i], b, acc[i][j], 0, 0, 0);
            if constexpr (GATE) {
                i32x4 b2 = *reinterpret_cast<const i32x4*>(&B2ls[ks][wc*64 + j*16 + fr][0]);
#pragma unroll
                for (int i = 0; i < 4; ++i)
                    acc2[i][j] = __builtin_amdgcn_mfma_i32_16x16x64_i8(a[i], b2, acc2[i][j], 0, 0, 0);
            }
        }
        __syncthreads();
    }

    // epilogue: f64 dequant.  C/D map: col=lane&15, row=(lane>>4)*4+reg
#pragma unroll
    for (int i = 0; i < 4; ++i) {
#pragma unroll
        for (int r = 0; r < 4; ++r) {
            int row = m0 + wr*64 + i*16 + (lane>>4)*4 + r;
            if (row >= M) continue;
            double mul = dqw / ascale[row];
#pragma unroll
            for (int j = 0; j < 4; ++j) {
                int col = n0 + wc*64 + j*16 + (lane & 15);
                if (col >= N) continue;
                size_t o = (size_t)row*N + col;
                if constexpr (GATE) {
                    double g = (double)acc[i][j][r] * mul;
                    double y = (double)acc2[i][j][r] * mul;
                    C[o] = g/(1.0+exp(-g)) * y;
                } else {
                    double v = (double)acc[i][j][r] * mul;
                    if (bias) v += (double)bias[col];
                    C[o] = accum ? C[o] + v : v;
                }
            }
        }
    }
}

// ---------------------------------------------------------------------------
extern "C" void kernel_launch(void* const* d_in, const int* in_sizes, int n_in,
                              void* d_out, int out_size, void* d_ws, size_t ws_size,
                              hipStream_t stream)
{
    (void)in_sizes; (void)n_in; (void)out_size;
    auto in = [&](int i){ return (const float*)d_in[i]; };

    const float *X = in(0), *T = in(1), *Y = in(2), *XC = in(3), *REF = in(4);
    const float *xe_w = in(6), *xe_b = in(7), *pos = in(8);
    const float *te_w1 = in(9), *te_b1 = in(10), *te_w2 = in(11), *te_b2 = in(12);
    const float *pp_w = in(13), *pp_b = in(14);
    const float *sa_pe_w = in(15), *sa_pe_b = in(16);
    const float *sa_ln_g = in(17), *sa_ln_b = in(18);
    const float *sa_gate_w = in(19), *sa_down_w = in(20);
    const float *sa_dc_w = in(21), *sa_dc_b = in(22);
    const float *ada_w = in(23), *ada_b = in(24);
    const float *sa_wi = in(25), *sa_wf = in(26), *sa_wg = in(27), *sa_wo = in(28);
    const float *mv_wi = in(29), *mv_wf = in(30), *mv_wg = in(31), *mv_wo = in(32);
    const float *rf_wi = in(33), *rf_wf = in(34), *rf_wg = in(35), *rf_wo = in(36);
    const float *gate_w = in(37), *down_w = in(38);
    const float *fl_w = in(39), *fl_b = in(40), *fl_ada_w = in(41), *fl_ada_b = in(42);
    float* OUT = (float*)d_out;

    // ---------- workspace layout (base ~223 MB; W8 optional +101 MB) -------
    size_t off = 0;
    auto AL = [&](size_t bytes){ off = (off+255)&~(size_t)255; size_t r = off; off += bytes; return r; };
    const size_t oScale = AL(37*8);
    const size_t oPart  = AL(37*32*8);
    const size_t oSM1 = AL(8*1152*8), oSM2 = AL(8*1152*8), oSM3 = AL(8*1152*8);
    const size_t oCB  = AL(8*1152*8);
    const size_t oMOD = AL(8*6912*8);
    const size_t oH   = AL((size_t)8192*1152*8);    // 75.5 MB; reused as OB later
    const size_t oINT = AL((size_t)1024*4608*8);    // 37.7 MB (1024-row chunks)
    const size_t oF0  = AL((size_t)2048*1152*8);    // also ACC in block loop
    const size_t oXT  = AL((size_t)2048*1152*8);
    const size_t oFB  = AL((size_t)2048*1152*8);
    const size_t oIB  = AL((size_t)2048*1152*8);
    const size_t oGB  = AL((size_t)2048*1152*8);
    const size_t oRO  = AL((size_t)512*1152*8);
    const size_t oQ8X = AL((size_t)2048*1152);
    const size_t oQ8I = AL((size_t)1024*4608);
    const size_t oQ8O = AL((size_t)2048*1152);
    const size_t oQ8R = AL((size_t)512*1152);
    const size_t oQ8T = AL((size_t)8*1152);
    const size_t oQ8C = AL((size_t)8*1152);
    const size_t oDSX = AL(2048*8), oDSI = AL(1024*8), oDSO = AL(2048*8);
    const size_t oDSR = AL(512*8),  oDST = AL(8*8),    oDSC = AL(8*8);
    if (off > ws_size) return;

    // ---------- weight list + optional pre-ternarized region ----------
    WList wl{}; WOffs wo{};
    long long wn[37];
    int nw = 0;
    auto addw = [&](const float* w, long long n){ wl.p[nw]=w; wl.n[nw]=n; wn[nw]=n; nw++; };
    addw(te_w1, 294912); addw(te_w2, 1327104); addw(pp_w, 884736);
    addw(sa_gate_w, 10616832); addw(sa_down_w, 5308416);
    for (int l = 0; l < 2; ++l) {
        addw(ada_w + (size_t)l*7962624, 7962624);
        addw(sa_wi + (size_t)l*1327104, 1327104);
        addw(sa_wf + (size_t)l*1327104, 1327104);
        addw(sa_wg + (size_t)l*1327104, 1327104);
        addw(sa_wo + (size_t)l*1327104, 1327104);
        addw(mv_wi + (size_t)l*1327104, 1327104);
        addw(mv_wf + (size_t)l*1327104, 1327104);
        addw(mv_wg + (size_t)l*1327104, 1327104);
        addw(mv_wo + (size_t)l*1327104, 1327104);
        addw(rf_wi + (size_t)l*1327104, 1327104);
        addw(rf_wf + (size_t)l*1327104, 1327104);
        addw(rf_wg + (size_t)l*1327104, 1327104);
        addw(rf_wo + (size_t)l*1327104, 1327104);
        addw(gate_w + (size_t)l*10616832, 10616832);
        addw(down_w + (size_t)l*5308416, 5308416);
    }
    addw(fl_ada_w, 2654208); addw(fl_w, 36864);

    size_t off_saved = off;
    long long wtot = 0;
    for (int i = 0; i < 37; ++i) { wo.o[i] = wtot; wtot += (wn[i] + 255) & ~255LL; }
    const size_t oW8 = AL((size_t)wtot);
    const bool useW8 = (off <= ws_size);
    if (!useW8) off = off_saved;

    char* w8p = (char*)d_ws;
    double* scales = (double*)(w8p + oScale);
    double* parts  = (double*)(w8p + oPart);
    double *SM1=(double*)(w8p+oSM1), *SM2=(double*)(w8p+oSM2), *SM3=(double*)(w8p+oSM3);
    double *CB=(double*)(w8p+oCB), *MOD=(double*)(w8p+oMOD);
    double *H=(double*)(w8p+oH), *INT=(double*)(w8p+oINT);
    double *F0=(double*)(w8p+oF0), *XT=(double*)(w8p+oXT);
    double *FB=(double*)(w8p+oFB), *IB=(double*)(w8p+oIB), *GB=(double*)(w8p+oGB);
    double *ACC=F0, *OB=H, *RO=(double*)(w8p+oRO);
    signed char *Q8X=(signed char*)(w8p+oQ8X), *Q8I=(signed char*)(w8p+oQ8I);
    signed char *Q8O=(signed char*)(w8p+oQ8O), *Q8R=(signed char*)(w8p+oQ8R);
    signed char *Q8T=(signed char*)(w8p+oQ8T), *Q8C=(signed char*)(w8p+oQ8C);
    double *DSX=(double*)(w8p+oDSX), *DSI=(double*)(w8p+oDSI), *DSO=(double*)(w8p+oDSO);
    double *DSR=(double*)(w8p+oDSR), *DST=(double*)(w8p+oDST), *DSC=(double*)(w8p+oDSC);
    signed char* W8 = (signed char*)(w8p + oW8);

    // ---------- weight scales (+ one-time ternarize) ----------
    k_abssum_all<<<dim3(32,37), 256, 0, stream>>>(wl, parts);
    k_abssum_fin<<<37, 64, 0, stream>>>(parts, scales);
    if (useW8)
        k_ternarize<<<dim3(64,37), 256, 0, stream>>>(wl, wo, scales, W8);

    // ---------- launch helpers ----------
    auto qgemm = [&](const signed char* A8, const double* as, const float* Win, int slot,
                     const float* b, double* Cout, int M, int N, int K, int accum){
        dim3 g((unsigned)((M+127)/128), (unsigned)((N+127)/128));
        if (useW8)
            k_qgemm<0,1><<<g, 256, 0, stream>>>(A8, as, Win, W8 + wo.o[slot],
                                                scales+slot, wn[slot], b, Cout, M, N, K, accum);
        else
            k_qgemm<0,0><<<g, 256, 0, stream>>>(A8, as, Win, nullptr,
                                                scales+slot, wn[slot], b, Cout, M, N, K, accum);
    };
    auto qgemmGate = [&](const signed char* A8, const double* as, const float* Win, int slot,
                         double* Cout, int M){
        dim3 g((unsigned)((M+127)/128), 36u);
        if (useW8)
            k_qgemm<1,1><<<g, 256, 0, stream>>>(A8, as, Win, W8 + wo.o[slot],
                                                scales+slot, wn[slot], nullptr, Cout, M, 4608, 1152, 0);
        else
            k_qgemm<1,0><<<g, 256, 0, stream>>>(A8, as, Win, nullptr,
                                                scales+slot, wn[slot], nullptr, Cout, M, 4608, 1152, 0);
    };

    // ---------- conditioning vector c ----------
    k_temb<<<8, 128, 0, stream>>>(T, SM1);
    k_rsq8<double><<<8, 256, 0, stream>>>(SM1, Q8T, DST, 256, 0);
    qgemm(Q8T, DST, te_w1, 0, te_b1, SM3, 8, 1152, 256, 0);
    k_rsq8<double><<<8, 256, 0, stream>>>(SM3, Q8T, DST, 1152, 1);
    qgemm(Q8T, DST, te_w2, 1, te_b2, SM2, 8, 1152, 1152, 0);
    k_rsq8<float><<<8, 256, 0, stream>>>(Y, Q8T, DST, 768, 0);
    qgemm(Q8T, DST, pp_w, 2, pp_b, SM3, 8, 1152, 768, 0);
    k_add<<<36, 256, 0, stream>>>(SM2, SM3, CB, 9216);
    k_rsq8<double><<<8, 256, 0, stream>>>(CB, Q8C, DSC, 1152, 1);

    // ---------- spatial adapter: patch embed + block 0 only ----------
    k_dgemm<1,0><<<dim3(18,128), 256, 0, stream>>>(XC, sa_pe_w, sa_pe_b, H, 8192, 1152, 1536);
    for (int ch = 0; ch < 8; ++ch) {
        double* Hrow = H + (size_t)ch*1024*1152;
        k_lnq8<<<1024, 256, 1152*8, stream>>>(Hrow, Q8X, DSX, 1152, sa_ln_g, sa_ln_b,
                                              nullptr, nullptr, 0, 1e-5);
        qgemmGate(Q8X, DSX, sa_gate_w, 3, INT, 1024);
        k_rsq8<double><<<1024, 256, 0, stream>>>(INT, Q8I, DSI, 4608, 0);
        qgemm(Q8I, DSI, sa_down_w, 4, nullptr, Hrow, 1024, 1152, 4608, 0);
    }
    k_dgemm<2,1><<<dim3(18,32), 256, 0, stream>>>(H, sa_dc_w, sa_dc_b, F0, 2048, 1152, 4608);

    // ---------- patchify latents + pos + feats0 ----------
    k_patchify<<<9216, 256, 0, stream>>>(X, xe_w, xe_b, pos, F0, XT);
    k_rsq8<float><<<512, 256, 0, stream>>>(REF, Q8R, DSR, 1152, 0);

    // ---------- transformer blocks (OB aliases dead H) ----------
    for (int l = 0; l < 2; ++l) {
        int sb = 5 + l*15;
        const float *wada = ada_w + (size_t)l*7962624, *bada = ada_b + (size_t)l*6912;
        const float *swi = sa_wi + (size_t)l*1327104, *swf = sa_wf + (size_t)l*1327104;
        const float *swg = sa_wg + (size_t)l*1327104, *swo = sa_wo + (size_t)l*1327104;
        const float *mwi = mv_wi + (size_t)l*1327104, *mwf = mv_wf + (size_t)l*1327104;
        const float *mwg = mv_wg + (size_t)l*1327104, *mwo = mv_wo + (size_t)l*1327104;
        const float *rwi = rf_wi + (size_t)l*1327104, *rwf = rf_wf + (size_t)l*1327104;
        const float *rwg = rf_wg + (size_t)l*1327104, *rwo = rf_wo + (size_t)l*1327104;
        const float *wgt = gate_w + (size_t)l*10616832, *wdn = down_w + (size_t)l*5308416;

        qgemm(Q8C, DSC, wada, sb+0, bada, MOD, 8, 6912, 1152, 0);

        k_lnq8<<<2048, 256, 1152*8, stream>>>(XT, Q8X, DSX, 1152, nullptr, nullptr,
                                              MOD+0, MOD+1152, 6912, 1e-6);

        // self attention (seq = 256 tokens)
        qgemm(Q8X, DSX, swf, sb+2, nullptr, FB, 2048, 1152, 1152, 0);
        qgemm(Q8X, DSX, swi, sb+1, nullptr, IB, 2048, 1152, 1152, 0);
        qgemm(Q8X, DSX, swg, sb+3, nullptr, GB, 2048, 1152, 1152, 0);
        k_gatepre<<<9216, 256, 0, stream>>>(FB, IB, 2359296LL);
        k_scan2<<<36, 256, 0, stream>>>(FB, IB, OB, 8, 294912LL, 1152, 1152LL, 256);
        k_ogateq8<<<2048, 256, 1152*8, stream>>>(OB, GB, Q8O, DSO, 1152);
        qgemm(Q8O, DSO, swo, sb+4, nullptr, ACC, 2048, 1152, 1152, 0);

        // multi-view attention (seq = 4 views; token layout unchanged)
        qgemm(Q8X, DSX, mwf, sb+6, nullptr, FB, 2048, 1152, 1152, 0);
        qgemm(Q8X, DSX, mwi, sb+5, nullptr, IB, 2048, 1152, 1152, 0);
        qgemm(Q8X, DSX, mwg, sb+7, nullptr, GB, 2048, 1152, 1152, 0);
        k_gatepre<<<9216, 256, 0, stream>>>(FB, IB, 2359296LL);
        k_scan2<<<2304, 256, 0, stream>>>(FB, IB, OB, 2, 1179648LL, 294912, 294912LL, 4);
        k_ogateq8<<<2048, 256, 1152*8, stream>>>(OB, GB, Q8O, DSO, 1152);
        qgemm(Q8O, DSO, mwo, sb+8, nullptr, ACC, 2048, 1152, 1152, 1);   // +=

        // ref attention on 2 unique batches
        qgemm(Q8R, DSR, rwf, sb+10, nullptr, FB, 512, 1152, 1152, 0);
        qgemm(Q8R, DSR, rwi, sb+9,  nullptr, IB, 512, 1152, 1152, 0);
        qgemm(Q8R, DSR, rwg, sb+11, nullptr, GB, 512, 1152, 1152, 0);
        k_gatepre<<<2304, 256, 0, stream>>>(FB, IB, 589824LL);
        k_scan2<<<9, 256, 0, stream>>>(FB, IB, OB, 2, 294912LL, 1152, 1152LL, 256);
        k_ogateq8<<<512, 256, 1152*8, stream>>>(OB, GB, Q8O, DSO, 1152);
        qgemm(Q8O, DSO, rwo, sb+12, nullptr, RO, 512, 1152, 1152, 0);

        k_resid_attn<<<9216, 256, 0, stream>>>(XT, ACC, RO, MOD);

        // MLP (1024-row chunks through INT)
        k_lnq8<<<2048, 256, 1152*8, stream>>>(XT, Q8X, DSX, 1152, nullptr, nullptr,
                                              MOD+3*1152, MOD+4*1152, 6912, 1e-6);
        for (int ch = 0; ch < 2; ++ch) {
            qgemmGate(Q8X + (size_t)ch*1024*1152, DSX + ch*1024, wgt, sb+13, INT, 1024);
            k_rsq8<double><<<1024, 256, 0, stream>>>(INT, Q8I, DSI, 4608, 0);
            qgemm(Q8I, DSI, wdn, sb+14, nullptr, OB + (size_t)ch*1024*1152, 1024, 1152, 4608, 0);
        }
        k_resid_mlp<<<9216, 256, 0, stream>>>(XT, OB, MOD);
    }

    // ---------- final layer + unpatchify ----------
    qgemm(Q8C, DSC, fl_ada_w, 35, fl_ada_b, MOD, 8, 2304, 1152, 0);
    k_lnq8<<<2048, 256, 1152*8, stream>>>(XT, Q8X, DSX, 1152, nullptr, nullptr,
                                          MOD+0, MOD+1152, 2304, 1e-6);
    qgemm(Q8X, DSX, fl_w, 36, fl_b, FB, 2048, 32, 1152, 0);
    k_unpatch<<<256, 256, 0, stream>>>(FB, OUT);
}